// Round 1
// baseline (138.179 us; speedup 1.0000x reference)
//
#include <hip/hip_runtime.h>

// LoopEmbeddingNetwork: B=200000 loops x L=8 strokes.
// gather(6) -> fc1(6->32,relu) -> fc2(32->16) -> MHA(E=16,H=2) -> [out_proj+fc fused](16->32,relu)
// -> mean over L -> fco(32->32).
// Mapping: 1 thread per (loop,token); 8 consecutive lanes = 1 loop; all
// cross-token traffic via intra-wave shuffles. Weights read via uniform
// addresses (scalar loads). out_proj/fc folded into W3/b3 in d_ws.

__global__ __launch_bounds__(512) void fuse_proj_kernel(
    const float* __restrict__ fc_w, const float* __restrict__ fc_b,
    const float* __restrict__ op_w, const float* __restrict__ op_b,
    float* __restrict__ w3, float* __restrict__ b3)
{
    int t = threadIdx.x;           // 512 threads: o = t>>4 (0..31), j = t&15
    int o = t >> 4, j = t & 15;
    float acc = 0.f;
#pragma unroll
    for (int e = 0; e < 16; ++e)
        acc = fmaf(fc_w[o * 16 + e], op_w[e * 16 + j], acc);
    w3[o * 16 + j] = acc;
    if (j == 0) {
        float bb = fc_b[o];
#pragma unroll
        for (int e = 0; e < 16; ++e)
            bb = fmaf(fc_w[o * 16 + e], op_b[e], bb);
        b3[o] = bb;
    }
}

__global__ __launch_bounds__(256) void loop_embed_kernel(
    const float* __restrict__ nf,   // [N,6]
    const int*   __restrict__ s2l,  // [B,8] (int32 per harness)
    const float* __restrict__ w1, const float* __restrict__ b1,   // 32x6, 32
    const float* __restrict__ w2, const float* __restrict__ b2,   // 16x32, 16
    const float* __restrict__ wip, const float* __restrict__ bip, // 48x16, 48
    const float* __restrict__ w3, const float* __restrict__ b3,   // 32x16, 32 (fused)
    const float* __restrict__ fow, const float* __restrict__ fob, // 32x32, 32
    float* __restrict__ out, int B)
{
    int tid = blockIdx.x * 256 + threadIdx.x;
    int b = tid >> 3;
    if (b >= B) return;
    int l = tid & 7;

    // ---- gather 6 node features (table is L2-resident: 2.4 MB) ----
    int idx = s2l[b * 8 + l];
    const float2* nfp = reinterpret_cast<const float2*>(nf);
    float2 p0 = nfp[idx * 3 + 0];
    float2 p1 = nfp[idx * 3 + 1];
    float2 p2 = nfp[idx * 3 + 2];
    float f[6] = {p0.x, p0.y, p1.x, p1.y, p2.x, p2.y};

    // ---- fc1: 6 -> 32, relu ----
    float h[32];
#pragma unroll
    for (int o = 0; o < 32; ++o) {
        float acc = b1[o];
#pragma unroll
        for (int i = 0; i < 6; ++i) acc = fmaf(f[i], w1[o * 6 + i], acc);
        h[o] = fmaxf(acc, 0.f);
    }

    // ---- fc2: 32 -> 16 ----
    float x[16];
#pragma unroll
    for (int e = 0; e < 16; ++e) {
        float acc = b2[e];
#pragma unroll
        for (int i = 0; i < 32; ++i) acc = fmaf(h[i], w2[e * 32 + i], acc);
        x[e] = acc;
    }

    // ---- in_proj: 16 -> 48 (q,k,v) ----
    float q[16], k[16], v[16];
#pragma unroll
    for (int c = 0; c < 16; ++c) {
        float aq = bip[c], ak = bip[16 + c], av = bip[32 + c];
#pragma unroll
        for (int e = 0; e < 16; ++e) {
            aq = fmaf(x[e], wip[c * 16 + e], aq);
            ak = fmaf(x[e], wip[(16 + c) * 16 + e], ak);
            av = fmaf(x[e], wip[(32 + c) * 16 + e], av);
        }
        q[c] = aq; k[c] = ak; v[c] = av;
    }

    // ---- attention scores: s[h][m] = q_h . k_h(m), via intra-wave shuffles ----
    int lane = threadIdx.x & 63;
    int gb = lane & 56;             // base lane of this loop's 8-thread group
    float s0[8], s1[8];
#pragma unroll
    for (int m = 0; m < 8; ++m) {
        float a0 = 0.f, a1 = 0.f;
#pragma unroll
        for (int d = 0; d < 8; ++d) {
            float k0 = __shfl(k[d],     gb + m, 64);
            float k1 = __shfl(k[8 + d], gb + m, 64);
            a0 = fmaf(q[d],     k0, a0);
            a1 = fmaf(q[8 + d], k1, a1);
        }
        s0[m] = a0; s1[m] = a1;
    }

    // ---- softmax per head (scale 1/sqrt(8)) ----
    const float sc = 0.35355339059327373f;
    float mx0 = s0[0], mx1 = s1[0];
#pragma unroll
    for (int m = 1; m < 8; ++m) { mx0 = fmaxf(mx0, s0[m]); mx1 = fmaxf(mx1, s1[m]); }
    float e0[8], e1[8];
    float sum0 = 0.f, sum1 = 0.f;
#pragma unroll
    for (int m = 0; m < 8; ++m) {
        e0[m] = __expf((s0[m] - mx0) * sc); sum0 += e0[m];
        e1[m] = __expf((s1[m] - mx1) * sc); sum1 += e1[m];
    }
    float r0 = 1.0f / sum0, r1 = 1.0f / sum1;

    // ---- ctx = softmax . v  (shuffle v across the group) ----
    float ctx[16];
#pragma unroll
    for (int c = 0; c < 16; ++c) ctx[c] = 0.f;
#pragma unroll
    for (int m = 0; m < 8; ++m) {
#pragma unroll
        for (int c = 0; c < 8; ++c) {
            float vv = __shfl(v[c], gb + m, 64);
            ctx[c] = fmaf(e0[m], vv, ctx[c]);
        }
#pragma unroll
        for (int c = 8; c < 16; ++c) {
            float vv = __shfl(v[c], gb + m, 64);
            ctx[c] = fmaf(e1[m], vv, ctx[c]);
        }
    }
#pragma unroll
    for (int c = 0; c < 8; ++c)  ctx[c] *= r0;
#pragma unroll
    for (int c = 8; c < 16; ++c) ctx[c] *= r1;

    // ---- fused out_proj+fc: 16 -> 32, relu ----
    float y[32];
#pragma unroll
    for (int o = 0; o < 32; ++o) {
        float acc = b3[o];
#pragma unroll
        for (int j = 0; j < 16; ++j) acc = fmaf(ctx[j], w3[o * 16 + j], acc);
        y[o] = fmaxf(acc, 0.f);
    }

    // ---- mean over 8 tokens: butterfly within the 8-lane group ----
#pragma unroll
    for (int o = 0; o < 32; ++o) {
        y[o] += __shfl_xor(y[o], 1, 64);
        y[o] += __shfl_xor(y[o], 2, 64);
        y[o] += __shfl_xor(y[o], 4, 64);
    }

    // ---- fco: 32 -> 32; each of the 8 threads computes 4 outputs ----
    float o4[4];
#pragma unroll
    for (int j = 0; j < 4; ++j) {
        int oo = l * 4 + j;
        float acc = 0.f;
#pragma unroll
        for (int i = 0; i < 32; ++i) acc = fmaf(y[i], fow[oo * 32 + i], acc);
        o4[j] = fmaf(acc, 0.125f, fob[oo]);  // fold mean's 1/8
    }
    reinterpret_cast<float4*>(out)[b * 8 + l] = make_float4(o4[0], o4[1], o4[2], o4[3]);
}

extern "C" void kernel_launch(void* const* d_in, const int* in_sizes, int n_in,
                              void* d_out, int out_size, void* d_ws, size_t ws_size,
                              hipStream_t stream) {
    const float* nf  = (const float*)d_in[0];
    const int*   s2l = (const int*)d_in[1];
    const float* w1  = (const float*)d_in[2];
    const float* b1  = (const float*)d_in[3];
    const float* w2  = (const float*)d_in[4];
    const float* b2  = (const float*)d_in[5];
    const float* wip = (const float*)d_in[6];
    const float* bip = (const float*)d_in[7];
    const float* opw = (const float*)d_in[8];
    const float* opb = (const float*)d_in[9];
    const float* fcw = (const float*)d_in[10];
    const float* fcb = (const float*)d_in[11];
    const float* fow = (const float*)d_in[12];
    const float* fob = (const float*)d_in[13];
    float* out = (float*)d_out;

    float* w3 = (float*)d_ws;       // 512 floats
    float* b3 = w3 + 512;           // 32 floats

    int B = in_sizes[1] / 8;
    fuse_proj_kernel<<<1, 512, 0, stream>>>(fcw, fcb, opw, opb, w3, b3);

    int total = B * 8;
    int blocks = (total + 255) / 256;
    loop_embed_kernel<<<blocks, 256, 0, stream>>>(nf, s2l, w1, b1, w2, b2,
                                                  wip, bip, w3, b3, fow, fob,
                                                  out, B);
    (void)n_in; (void)out_size; (void)ws_size;
}